// Round 10
// baseline (71.456 us; speedup 1.0000x reference)
//
#include <hip/hip_runtime.h>
#include <math.h>

#define ALPHA 5e-4f
#define BIG 1e30f

typedef __attribute__((ext_vector_type(4))) float f32x4;

__device__ __forceinline__ void gload16(const void* g, void* l) {
    __builtin_amdgcn_global_load_lds(
        (const __attribute__((address_space(1))) void*)g,
        (__attribute__((address_space(3))) void*)l, 16, 0, 0);
}

// ---------------- Kernel A: f32 -> fp8(e4m3) convert + exact f32 row norms ----------------
__global__ __launch_bounds__(256)
void conv_fp8_kernel(const float* __restrict__ X, unsigned char* __restrict__ Xq,
                     float* __restrict__ sqn32, int d) {
    const int w = threadIdx.x >> 6, lane = threadIdx.x & 63;
    const int row = blockIdx.x * 4 + w;
    const float4* src = reinterpret_cast<const float4*>(X + (size_t)row * d);
    int4* dst = reinterpret_cast<int4*>(Xq + (size_t)row * d);
    float s = 0.f;
    const int ng = d >> 4;                 // 16 floats / group
    for (int g = lane; g < ng; g += 64) {
        int wds[4];
#pragma unroll
        for (int q = 0; q < 4; ++q) {
            float4 v = src[g * 4 + q];
            s += v.x * v.x + v.y * v.y + v.z * v.z + v.w * v.w;
            int t0 = __builtin_amdgcn_cvt_pk_fp8_f32(v.x, v.y, 0, false);
            wds[q] = __builtin_amdgcn_cvt_pk_fp8_f32(v.z, v.w, t0, true);
        }
        dst[g] = make_int4(wds[0], wds[1], wds[2], wds[3]);
    }
    for (int off = 1; off < 64; off <<= 1) s += __shfl_xor(s, off, 64);
    if (lane == 0) sqn32[row] = s;
}

// ---------------- Kernel B: fp8 MFMA gram, BKB=128, upper triangle, fused top-2 ----------------
// 128x128 tile, BKB=128 bytes -> only 8 K-steps (per-step barrier overhead is
// the measured invariant cost; minimize step count).  256 threads = 4 waves
// (2x2), 2-stage double buffer (64 KB LDS), counted vmcnt(8).
// LDS swizzle: 128B rows; stored 16B-chunk c holds global chunk c ^ (row&7)
// (source offset ((l&7)^(l>>3))<<4, gload16-compatible); reads (8B units) at
// sub8' = (ki*4+lg) ^ ((lc&7)<<1)  -> b64-optimal 4-way banks.
// Selection value s = sqn32[col] - 2*<xq_i,xq_j>  (bias-free metric).
#define BM 128
#define BN 128
#define BKB 128

__global__ __launch_bounds__(256)
void gram_top2_mfma(const unsigned char* __restrict__ Xq, const float* __restrict__ sqn,
                    float* __restrict__ cand_s, int* __restrict__ cand_i,
                    int n, int d, int nb, int cpx) {
    __shared__ unsigned char As[2][BM * BKB];   // 2 x 16KB
    __shared__ unsigned char Bs[2][BN * BKB];   // 2 x 16KB

    // flat XCD chunking, then triangular decode
    const int bid = blockIdx.x;
    int rem = (bid & 7) * cpx + (bid >> 3);
    int rb = 0;
    while (rem >= nb - rb) { rem -= nb - rb; ++rb; }
    const int cb = rb + rem;

    const int row0 = rb * BM, col0 = cb * BN;
    const int t = threadIdx.x;
    const int w = t >> 6, l = t & 63;
    const int wr = w >> 1, wc = w & 1;
    const int lc = l & 15, lg = l >> 4;

    f32x4 acc[4][4];
#pragma unroll
    for (int i = 0; i < 4; ++i)
#pragma unroll
        for (int j = 0; j < 4; ++j) acc[i][j] = (f32x4){0.f, 0.f, 0.f, 0.f};

    // staging: wave w, instr p writes LDS bytes [w*1024+p*4096, +1024):
    // lane l -> row w*8+p*32+(l>>3), stored chunk l&7, source chunk (l&7)^(l>>3)
    const int srow = w * 8 + (l >> 3);
    const int gsw = ((l & 7) ^ (l >> 3)) << 4;
    const size_t gA0 = (size_t)(row0 + srow) * d + gsw;
    const size_t gB0 = (size_t)(col0 + srow) * d + gsw;
    const int ldsw = w * 1024;

    const int nsteps = d / BKB;            // 8

#define STAGE(stg, ks)                                                        \
    {                                                                         \
        const size_t ko = (size_t)(ks) * BKB;                                 \
        _Pragma("unroll")                                                     \
        for (int p = 0; p < 4; ++p) {                                         \
            gload16(Xq + gA0 + ko + (size_t)p * 32 * d, As[stg] + ldsw + p * 4096); \
            gload16(Xq + gB0 + ko + (size_t)p * 32 * d, Bs[stg] + ldsw + p * 4096); \
        }                                                                     \
    }

    // prologue: stage 0
    STAGE(0, 0)

    int cur = 0;
    for (int ks = 0; ks < nsteps; ++ks) {
        if (ks + 1 < nsteps) {
            STAGE(cur ^ 1, ks + 1)
            asm volatile("s_waitcnt vmcnt(8)" ::: "memory");   // stage ks landed
        } else {
            asm volatile("s_waitcnt vmcnt(0)" ::: "memory");
        }
        __builtin_amdgcn_s_barrier();      // stage ks visible to all waves

        long long a[4][4], b[4][4];
#pragma unroll
        for (int ki = 0; ki < 4; ++ki) {
            const int swz8 = ((ki * 4 + lg) ^ ((lc & 7) << 1)) << 3;
#pragma unroll
            for (int mi = 0; mi < 4; ++mi) {
                a[ki][mi] = *reinterpret_cast<const long long*>(
                    &As[cur][(wr * 64 + mi * 16 + lc) * BKB + swz8]);
                b[ki][mi] = *reinterpret_cast<const long long*>(
                    &Bs[cur][(wc * 64 + mi * 16 + lc) * BKB + swz8]);
            }
        }
        __builtin_amdgcn_s_setprio(1);
#pragma unroll
        for (int ki = 0; ki < 4; ++ki)
#pragma unroll
            for (int mi = 0; mi < 4; ++mi)
#pragma unroll
                for (int ni = 0; ni < 4; ++ni)
                    acc[mi][ni] = __builtin_amdgcn_mfma_f32_16x16x32_fp8_fp8(
                        a[ki][mi], b[ki][ni], acc[mi][ni], 0, 0, 0);
        __builtin_amdgcn_s_setprio(0);

        asm volatile("s_waitcnt lgkmcnt(0)" ::: "memory");
        __builtin_amdgcn_s_barrier();      // reads of cur done -> cur reusable
        cur ^= 1;
    }
#undef STAGE

    // ---- row-path epilogue: per-row top-2 over this wave's 64-col strip ----
    // C frag layout: col = lane&15, row = (lane>>4)*4 + reg.
    float sq_c[4];
#pragma unroll
    for (int ni = 0; ni < 4; ++ni) sq_c[ni] = sqn[col0 + wc * 64 + ni * 16 + lc];
    const int strip_r = cb * 2 + wc;

#pragma unroll
    for (int mi = 0; mi < 4; ++mi) {
#pragma unroll
        for (int j = 0; j < 4; ++j) {
            const int grow = row0 + wr * 64 + mi * 16 + lg * 4 + j;
            float s1v = BIG, s2v = BIG;
            int i1 = -1, i2 = -1;
#pragma unroll
            for (int ni = 0; ni < 4; ++ni) {
                const int gcol = col0 + wc * 64 + ni * 16 + lc;
                float s = sq_c[ni] - 2.f * acc[mi][ni][j];
                if (gcol == grow) s = BIG;   // exclude self (diag blocks)
                if (s < s1v) { s2v = s1v; i2 = i1; s1v = s; i1 = gcol; }
                else if (s < s2v) { s2v = s; i2 = gcol; }
            }
            for (int off = 1; off < 16; off <<= 1) {
                float b1 = __shfl_xor(s1v, off, 16);
                int  bi1 = __shfl_xor(i1, off, 16);
                float b2 = __shfl_xor(s2v, off, 16);
                int  bi2 = __shfl_xor(i2, off, 16);
                if (b1 < s1v) { s2v = s1v; i2 = i1; s1v = b1; i1 = bi1; }
                else if (b1 < s2v) { s2v = b1; i2 = bi1; }
                if (b2 < s2v) { s2v = b2; i2 = bi2; }
            }
            if (lc == 0) {
                size_t base = ((size_t)grow * 64 + strip_r) * 2;
                cand_s[base] = s1v; cand_s[base + 1] = s2v;
                cand_i[base] = i1; cand_i[base + 1] = i2;
            }
        }
    }

    // ---- col-path epilogue (off-diagonal blocks): per-col top-2 over 64 rows ----
    if (rb != cb) {
        float sq_r[4][4];
#pragma unroll
        for (int mi = 0; mi < 4; ++mi)
#pragma unroll
            for (int j = 0; j < 4; ++j)
                sq_r[mi][j] = sqn[row0 + wr * 64 + mi * 16 + lg * 4 + j];
        const int strip_c = rb * 2 + wr;

#pragma unroll
        for (int ni = 0; ni < 4; ++ni) {
            const int gcol = col0 + wc * 64 + ni * 16 + lc;
            float s1v = BIG, s2v = BIG;
            int i1 = -1, i2 = -1;
#pragma unroll
            for (int mi = 0; mi < 4; ++mi)
#pragma unroll
                for (int j = 0; j < 4; ++j) {
                    const int grow = row0 + wr * 64 + mi * 16 + lg * 4 + j;
                    float s = sq_r[mi][j] - 2.f * acc[mi][ni][j];
                    if (s < s1v) { s2v = s1v; i2 = i1; s1v = s; i1 = grow; }
                    else if (s < s2v) { s2v = s; i2 = grow; }
                }
#pragma unroll
            for (int off = 16; off < 64; off <<= 1) {
                float b1 = __shfl_xor(s1v, off, 64);
                int  bi1 = __shfl_xor(i1, off, 64);
                float b2 = __shfl_xor(s2v, off, 64);
                int  bi2 = __shfl_xor(i2, off, 64);
                if (b1 < s1v) { s2v = s1v; i2 = i1; s1v = b1; i1 = bi1; }
                else if (b1 < s2v) { s2v = b1; i2 = bi1; }
                if (b2 < s2v) { s2v = b2; i2 = bi2; }
            }
            if (lg == 0) {
                size_t base = ((size_t)gcol * 64 + strip_c) * 2;
                cand_s[base] = s1v; cand_s[base + 1] = s2v;
                cand_i[base] = i1; cand_i[base + 1] = i2;
            }
        }
    }
}

// ---------------- Kernel C: merge 128 candidates/row + edge terms ----------------
__global__ __launch_bounds__(256)
void merge_edges_kernel(const float* __restrict__ sqn,
                        const float* __restrict__ cand_s, const int* __restrict__ cand_i,
                        const int* __restrict__ yb, const float* __restrict__ yo,
                        float* __restrict__ partial, int ncls) {
    const int w = threadIdx.x >> 6, lane = threadIdx.x & 63;
    const int row = blockIdx.x * 4 + w;

    float2 cs = reinterpret_cast<const float2*>(cand_s + (size_t)row * 128)[lane];
    int2   ci = reinterpret_cast<const int2*>(cand_i + (size_t)row * 128)[lane];
    float s1 = cs.x, s2 = cs.y;
    int i1 = ci.x, i2 = ci.y;
    if (s2 < s1) { float ts = s1; s1 = s2; s2 = ts; int ti = i1; i1 = i2; i2 = ti; }

    for (int off = 1; off < 64; off <<= 1) {
        float b1 = __shfl_xor(s1, off, 64);
        int  bi1 = __shfl_xor(i1, off, 64);
        float b2 = __shfl_xor(s2, off, 64);
        int  bi2 = __shfl_xor(i2, off, 64);
        if (b1 < s1) { s2 = s1; i2 = i1; s1 = b1; i1 = bi1; }
        else if (b1 < s2) { s2 = b1; i2 = bi1; }
        if (b2 < s2) { s2 = b2; i2 = bi2; }
    }
    const int yr = yb[row];
    const float sr = sqn[row];
    float w1 = ((yr == yb[i1]) ? 1.f : -1.f) * expf(-sqrtf(fmaxf(sr + s1, 0.f)));
    float w2 = ((yr == yb[i2]) ? 1.f : -1.f) * expf(-sqrtf(fmaxf(sr + s2, 0.f)));

    const float4* yr4 = reinterpret_cast<const float4*>(yo + (size_t)row * ncls);
    const float4* y14 = reinterpret_cast<const float4*>(yo + (size_t)i1 * ncls);
    const float4* y24 = reinterpret_cast<const float4*>(yo + (size_t)i2 * ncls);
    const int nv4 = ncls >> 2;             // 250
    float a1 = 0.f, a2 = 0.f;
    for (int c = lane; c < nv4; c += 64) {
        float4 v = yr4[c];
        float4 u1 = y14[c];
        float4 u2 = y24[c];
        float tx = v.x - u1.x, ty = v.y - u1.y, tz = v.z - u1.z, tw = v.w - u1.w;
        a1 = fmaf(tx, tx, fmaf(ty, ty, fmaf(tz, tz, fmaf(tw, tw, a1))));
        tx = v.x - u2.x; ty = v.y - u2.y; tz = v.z - u2.z; tw = v.w - u2.w;
        a2 = fmaf(tx, tx, fmaf(ty, ty, fmaf(tz, tz, fmaf(tw, tw, a2))));
    }
    for (int c = (nv4 << 2) + lane; c < ncls; c += 64) {   // tail (empty for 1000)
        float v = yo[(size_t)row * ncls + c];
        float t1 = v - yo[(size_t)i1 * ncls + c];
        float t2 = v - yo[(size_t)i2 * ncls + c];
        a1 = fmaf(t1, t1, a1);
        a2 = fmaf(t2, t2, a2);
    }
    for (int off = 1; off < 64; off <<= 1) {
        a1 += __shfl_xor(a1, off, 64);
        a2 += __shfl_xor(a2, off, 64);
    }
    if (lane == 0)
        partial[row] = w1 * sqrtf(a1) + w2 * sqrtf(a2);
}

// ---------------- Kernel D: final reduction of n partials ----------------
__global__ __launch_bounds__(256)
void final_reduce_kernel(const float* __restrict__ partial, float* __restrict__ out, int n) {
    const int t = threadIdx.x;
    __shared__ float red[4];
    float s = 0.f;
    const int nv4 = n >> 2;
    const float4* p4 = reinterpret_cast<const float4*>(partial);
    for (int c = t; c < nv4; c += 256) {
        float4 v = p4[c];
        s += v.x + v.y + v.z + v.w;
    }
    for (int off = 1; off < 64; off <<= 1) s += __shfl_xor(s, off, 64);
    if ((t & 63) == 0) red[t >> 6] = s;
    __syncthreads();
    if (t == 0) out[0] = ALPHA * (red[0] + red[1] + red[2] + red[3]);
}

extern "C" void kernel_launch(void* const* d_in, const int* in_sizes, int n_in,
                              void* d_out, int out_size, void* d_ws, size_t ws_size,
                              hipStream_t stream) {
    const float* X  = (const float*)d_in[0];
    const int*   yb = (const int*)d_in[1];
    const float* yo = (const float*)d_in[2];
    float* out = (float*)d_out;

    const int n    = in_sizes[1];          // 4096
    const int d    = in_sizes[0] / n;      // 1024
    const int ncls = in_sizes[2] / n;      // 1000
    const int nb   = n / BM;               // 32 row/col blocks of 128

    // workspace: sqn32 | Xq (fp8) | cand_s | cand_i | partial
    char* wsb = (char*)d_ws;
    size_t off = 0;
    float* sqn32 = (float*)(wsb + off);         off += ((size_t)n * 4 + 255) & ~(size_t)255;
    unsigned char* Xq = (unsigned char*)(wsb + off); off += ((size_t)n * d + 255) & ~(size_t)255;
    float* cand_s = (float*)(wsb + off);        off += ((size_t)n * 64 * 2 * 4 + 255) & ~(size_t)255;
    int*   cand_i = (int*)(wsb + off);          off += ((size_t)n * 64 * 2 * 4 + 255) & ~(size_t)255;
    float* partial = (float*)(wsb + off);

    conv_fp8_kernel<<<n / 4, 256, 0, stream>>>(X, Xq, sqn32, d);

    const int ntri = nb * (nb + 1) / 2;    // 528 = 66*8
    const int cpx  = ntri / 8;             // 66
    gram_top2_mfma<<<ntri, 256, 0, stream>>>(Xq, sqn32, cand_s, cand_i, n, d, nb, cpx);

    merge_edges_kernel<<<n / 4, 256, 0, stream>>>(sqn32, cand_s, cand_i, yb, yo, partial, ncls);

    final_reduce_kernel<<<1, 256, 0, stream>>>(partial, out, n);
}